// Round 3
// baseline (33623.938 us; speedup 1.0000x reference)
//
#include <hip/hip_runtime.h>
#include <hip/hip_cooperative_groups.h>

namespace cg = cooperative_groups;

// DCRNN encoder-decoder on MI355X.
// gso (8192x8192 dense fp32) is ~0.2% dense (~17 nnz/row, zeros exact).
// Build ELL once, then run ALL 48 GRU cells inside ONE persistent
// cooperative kernel (grid.sync between all-to-all stages) — R2 showed
// 194 small dispatches cost ~30us each in serialization; work is ~2us.

#define NV  8192   // n_vertex
#define TT  24     // time steps
#define BB  2      // batch
#define CC  33     // F + H per batch block
#define JJ  66     // BB * CC feature columns
#define HD  32     // hidden dim
#define CAP 64     // ELL capacity per row (degree ~Poisson(16))
#define NPB 8      // nodes per block in gate/cand stages
#define BLK 256
#define MAXGRID 1024   // 4 blocks/CU * 256 CU co-resident (VGPR<=128)

// ---------------- ELL build: one wave per row, float4 + ballot compaction --
__global__ __launch_bounds__(256) void build_ell(const float* __restrict__ gso,
                                                 int* __restrict__ ellc,
                                                 float* __restrict__ ellv,
                                                 int* __restrict__ rcnt) {
    int gtid = blockIdx.x * 256 + threadIdx.x;
    int row  = gtid >> 6;
    int lane = threadIdx.x & 63;
    if (row >= NV) return;
    const float* r = gso + (size_t)row * NV;
    int cnt = 0;
    const int base = row * CAP;
    for (int c0 = 0; c0 < NV; c0 += 256) {
        const float4 v = *reinterpret_cast<const float4*>(r + c0 + lane * 4);
        const float vv[4] = {v.x, v.y, v.z, v.w};
#pragma unroll
        for (int q = 0; q < 4; ++q) {
            unsigned long long m = __ballot(vv[q] != 0.0f);
            if (vv[q] != 0.0f) {
                int pos = cnt + __popcll(m & ((1ull << lane) - 1ull));
                if (pos < CAP) {
                    ellc[base + pos] = c0 + lane * 4 + q;
                    ellv[base + pos] = vv[q];
                }
            }
            cnt += __popcll(m);
        }
    }
    if (lane == 0) rcnt[row] = cnt < CAP ? cnt : CAP;
}

struct Params {
    const int*   ellc;
    const float* ellv;
    const int*   rcnt;
    const float* x;
    const float* eWr; const float* ebr;
    const float* eWu; const float* ebu;
    const float* eWc; const float* ebc;
    const float* dWr; const float* dbr;
    const float* dWu; const float* dbu;
    const float* dWc; const float* dbc;
    const float* W1;  const float* b1;
    const float* W2;  const float* b2;
    float* XH; float* X1; float* XC; float* Y1; float* U; float* out;
};

__device__ __forceinline__ void spmm_row2(const int* __restrict__ ellc,
                                          const float* __restrict__ ellv,
                                          int base, int cnt, int j2,
                                          const float* __restrict__ Xin,
                                          float2& acc) {
    acc.x = 0.f; acc.y = 0.f;
    for (int k = 0; k < cnt; ++k) {
        float s = ellv[base + k];
        const float2 xv = *reinterpret_cast<const float2*>(
            Xin + (size_t)ellc[base + k] * JJ + 2 * j2);
        acc.x = fmaf(s, xv.x, acc.x);
        acc.y = fmaf(s, xv.y, acc.y);
    }
}

__global__ __launch_bounds__(BLK, 4) void dcrnn_cells(Params P) {
    cg::grid_group grid = cg::this_grid();
    const int tid  = blockIdx.x * BLK + threadIdx.x;
    const int nthr = gridDim.x * BLK;
    __shared__ float s2[NPB][JJ];

    // ---- stage 0: XH = [x[:, t=0], h0 = 0] ----
    for (int idx = tid; idx < NV * JJ; idx += nthr) {
        int n = idx / JJ, j = idx - n * JJ;
        int b = j / CC, c = j - b * CC;
        P.XH[idx] = (c == 0) ? P.x[((size_t)b * TT) * NV + n] : 0.f;
    }
    grid.sync();

    for (int cell = 0; cell < 2 * TT; ++cell) {
        const bool enc = (cell < TT);
        const float* Wr = enc ? P.eWr : P.dWr;
        const float* br = enc ? P.ebr : P.dbr;
        const float* Wu = enc ? P.eWu : P.dWu;
        const float* bu = enc ? P.ebu : P.dbu;
        const float* Wc = enc ? P.eWc : P.dWc;
        const float* bc = enc ? P.ebc : P.dbc;
        // mode: 0 = next xin from x[t_next], 1 = zero, 2 = decoder pred
        const int mode   = enc ? ((cell + 1 < TT) ? 0 : 1) : 2;
        const int t_next = cell + 1;
        const int t_out  = cell - TT;

        // ---- S1: X1 = S @ XH ----
        for (int idx = tid; idx < NV * 33; idx += nthr) {
            int n = idx / 33, j2 = idx - n * 33;
            float2 acc;
            spmm_row2(P.ellc, P.ellv, n * CAP, P.rcnt[n], j2, P.XH, acc);
            *reinterpret_cast<float2*>(P.X1 + (size_t)n * JJ + 2 * j2) = acc;
        }
        grid.sync();

        // ---- S2: X2 = S @ X1 (LDS); r,u gates; XC = [xin, r*h] ----
        for (int grp = blockIdx.x; grp < NV / NPB; grp += gridDim.x) {
            int n0 = grp * NPB;
            for (int e = threadIdx.x; e < NPB * 33; e += BLK) {
                int ln = e / 33, j2 = e - ln * 33;
                int n = n0 + ln;
                float2 acc;
                spmm_row2(P.ellc, P.ellv, n * CAP, P.rcnt[n], j2, P.X1, acc);
                s2[ln][2 * j2]     = acc.x;
                s2[ln][2 * j2 + 1] = acc.y;
            }
            __syncthreads();
            for (int e = threadIdx.x; e < NPB * BB * HD; e += BLK) {
                int j  = e & 31;
                int p  = e >> 5;
                int ln = p >> 1;
                int b  = p & 1;
                int n  = n0 + ln;
                const float* xh = P.XH + (size_t)n * JJ + b * CC;
                const float* x1 = P.X1 + (size_t)n * JJ + b * CC;
                const float* x2 = &s2[ln][b * CC];
                float accr = br[j], accu = bu[j];
#pragma unroll
                for (int i = 0; i < CC; ++i) {
                    accr = fmaf(xh[i], Wr[i * HD + j], accr);
                    accu = fmaf(xh[i], Wu[i * HD + j], accu);
                }
#pragma unroll
                for (int i = 0; i < CC; ++i) {
                    accr = fmaf(x1[i], Wr[(CC + i) * HD + j], accr);
                    accu = fmaf(x1[i], Wu[(CC + i) * HD + j], accu);
                }
#pragma unroll
                for (int i = 0; i < CC; ++i) {
                    accr = fmaf(x2[i], Wr[(2 * CC + i) * HD + j], accr);
                    accu = fmaf(x2[i], Wu[(2 * CC + i) * HD + j], accu);
                }
                float rg = 1.f / (1.f + expf(-accr));
                float ug = 1.f / (1.f + expf(-accu));
                P.U[(size_t)n * 64 + b * HD + j] = ug;
                float h = xh[1 + j];
                P.XC[(size_t)n * JJ + b * CC + 1 + j] = rg * h;
                if (j == 0) P.XC[(size_t)n * JJ + b * CC] = xh[0];
            }
            __syncthreads();
        }
        grid.sync();

        // ---- S3: Y1 = S @ XC ----
        for (int idx = tid; idx < NV * 33; idx += nthr) {
            int n = idx / 33, j2 = idx - n * 33;
            float2 acc;
            spmm_row2(P.ellc, P.ellv, n * CAP, P.rcnt[n], j2, P.XC, acc);
            *reinterpret_cast<float2*>(P.Y1 + (size_t)n * JJ + 2 * j2) = acc;
        }
        grid.sync();

        // ---- S4: Y2 = S @ Y1 (LDS); c=tanh; h = u*h+(1-u)*c; next xin ----
        for (int grp = blockIdx.x; grp < NV / NPB; grp += gridDim.x) {
            int n0 = grp * NPB;
            for (int e = threadIdx.x; e < NPB * 33; e += BLK) {
                int ln = e / 33, j2 = e - ln * 33;
                int n = n0 + ln;
                float2 acc;
                spmm_row2(P.ellc, P.ellv, n * CAP, P.rcnt[n], j2, P.Y1, acc);
                s2[ln][2 * j2]     = acc.x;
                s2[ln][2 * j2 + 1] = acc.y;
            }
            __syncthreads();
            for (int e = threadIdx.x; e < NPB * BB * HD; e += BLK) {
                int j  = e & 31;
                int p  = e >> 5;
                int ln = p >> 1;
                int b  = p & 1;
                int n  = n0 + ln;
                const float* xc = P.XC + (size_t)n * JJ + b * CC;
                const float* y1 = P.Y1 + (size_t)n * JJ + b * CC;
                const float* y2 = &s2[ln][b * CC];
                float acc = bc[j];
#pragma unroll
                for (int i = 0; i < CC; ++i) acc = fmaf(xc[i], Wc[i * HD + j], acc);
#pragma unroll
                for (int i = 0; i < CC; ++i) acc = fmaf(y1[i], Wc[(CC + i) * HD + j], acc);
#pragma unroll
                for (int i = 0; i < CC; ++i) acc = fmaf(y2[i], Wc[(2 * CC + i) * HD + j], acc);
                float c = tanhf(acc);
                float u = P.U[(size_t)n * 64 + b * HD + j];
                float* hp = P.XH + (size_t)n * JJ + b * CC + 1 + j;
                float h = u * (*hp) + (1.f - u) * c;
                *hp = h;
                if (mode == 2) {
                    // decoder: z = relu(h @ W1 + b1); pred = z @ W2 + b2
                    float z = P.b1[j];
#pragma unroll
                    for (int i = 0; i < HD; ++i)
                        z = fmaf(__shfl(h, i, 32), P.W1[i * HD + j], z);
                    z = fmaxf(z, 0.f);
                    float pz = z * P.W2[j];
#pragma unroll
                    for (int off = 16; off; off >>= 1) pz += __shfl_xor(pz, off, 32);
                    if (j == 0) {
                        float pred = pz + P.b2[0];
                        P.out[((size_t)b * TT + t_out) * NV + n] = pred;
                        P.XH[(size_t)n * JJ + b * CC] = pred;
                    }
                } else if (j == 0) {
                    float xin = (mode == 0)
                        ? P.x[((size_t)b * TT + t_next) * NV + n] : 0.f;
                    P.XH[(size_t)n * JJ + b * CC] = xin;
                }
            }
            __syncthreads();
        }
        grid.sync();
    }
}

extern "C" void kernel_launch(void* const* d_in, const int* in_sizes, int n_in,
                              void* d_out, int out_size, void* d_ws, size_t ws_size,
                              hipStream_t stream) {
    const float* x      = (const float*)d_in[0];
    // d_in[1] = edge_index (unused; gso already encodes it)
    const float* gso    = (const float*)d_in[2];

    char* p = (char*)d_ws;
    auto alloc = [&](size_t bytes) {
        char* q = p;
        p += (bytes + 255) & ~(size_t)255;
        return q;
    };
    int*   ellc = (int*)  alloc((size_t)NV * CAP * 4);
    float* ellv = (float*)alloc((size_t)NV * CAP * 4);
    int*   rcnt = (int*)  alloc((size_t)NV * 4);
    float* XH   = (float*)alloc((size_t)NV * JJ * 4);
    float* X1   = (float*)alloc((size_t)NV * JJ * 4);
    float* XC   = (float*)alloc((size_t)NV * JJ * 4);
    float* Y1   = (float*)alloc((size_t)NV * JJ * 4);
    float* U    = (float*)alloc((size_t)NV * 64 * 4);

    hipLaunchKernelGGL(build_ell, dim3(NV / 4), dim3(256), 0, stream,
                       gso, ellc, ellv, rcnt);

    Params P;
    P.ellc = ellc; P.ellv = ellv; P.rcnt = rcnt;
    P.x    = x;
    P.eWr = (const float*)d_in[3];  P.ebr = (const float*)d_in[4];
    P.eWu = (const float*)d_in[5];  P.ebu = (const float*)d_in[6];
    P.eWc = (const float*)d_in[7];  P.ebc = (const float*)d_in[8];
    P.dWr = (const float*)d_in[9];  P.dbr = (const float*)d_in[10];
    P.dWu = (const float*)d_in[11]; P.dbu = (const float*)d_in[12];
    P.dWc = (const float*)d_in[13]; P.dbc = (const float*)d_in[14];
    P.W1  = (const float*)d_in[15]; P.b1  = (const float*)d_in[16];
    P.W2  = (const float*)d_in[17]; P.b2  = (const float*)d_in[18];
    P.XH = XH; P.X1 = X1; P.XC = XC; P.Y1 = Y1; P.U = U;
    P.out = (float*)d_out;

    // co-resident grid: query occupancy, cap at 4 blocks/CU * 256 CU
    int maxBlocksPerCU = 0;
    hipOccupancyMaxActiveBlocksPerMultiprocessor(&maxBlocksPerCU,
                                                 dcrnn_cells, BLK, 0);
    int grid = maxBlocksPerCU * 256;
    if (grid > MAXGRID) grid = MAXGRID;
    if (grid < 1) grid = 1;

    void* args[] = { (void*)&P };
    hipLaunchCooperativeKernel((void*)dcrnn_cells, dim3(grid), dim3(BLK),
                               args, 0, stream);
}

// Round 5
// 20828.220 us; speedup vs baseline: 1.6143x; 1.6143x over previous
//
#include <hip/hip_runtime.h>

// DCRNN encoder-decoder on MI355X (gfx950).
// gso (8192x8192 dense fp32) is ~0.2% dense (~17 nnz/row, zeros exact):
// build ELL once, then ONE persistent kernel runs all 48 GRU cells.
// R3 lesson: cg::grid.sync() costs ~175us/sync (system-scope L2 flush per
// block + 1024-spinner storm -> 38 GB HBM, VALUBusy 1.5%). Replace with a
// hand-rolled 2-level barrier: 256 blocks (1/CU co-resident), one arriver
// per block, 32 padded group counters -> root, s_sleep-backed spin on root
// only, agent-scope acq_rel fences.
// Layout: wave-per-node. Features split Xh[n][64] (lane = b*32+j hidden) +
// Xx[n][2] (x scalar per batch) so every diffusion gather is 17 coalesced
// 256B rows; gates/update fused in-wave via __shfl broadcast.

#define NV  8192
#define TT  24
#define CAP 64          // ELL capacity (row degree ~Poisson(17))
#define BLK 512         // 8 waves/block
#define GRD 256         // 1 block/CU -> co-resident
#define NGROUPS 32
#define BPG (GRD / NGROUPS)   // 8 blocks per barrier group

// ---------------- ELL build + barrier-counter zeroing ---------------------
__global__ __launch_bounds__(256) void build_ell(const float* __restrict__ gso,
                                                 int* __restrict__ ellc,
                                                 float* __restrict__ ellv,
                                                 int* __restrict__ rcnt,
                                                 unsigned* __restrict__ bar) {
    int gtid = blockIdx.x * 256 + threadIdx.x;
    if (gtid < 544) bar[gtid] = 0u;          // root + 32 padded group counters
    int row  = gtid >> 6;
    int lane = threadIdx.x & 63;
    if (row >= NV) return;
    const float* r = gso + (size_t)row * NV;
    int cnt = 0;
    const int base = row * CAP;
    for (int c0 = 0; c0 < NV; c0 += 256) {
        const float4 v = *reinterpret_cast<const float4*>(r + c0 + lane * 4);
        const float vv[4] = {v.x, v.y, v.z, v.w};
#pragma unroll
        for (int q = 0; q < 4; ++q) {
            unsigned long long m = __ballot(vv[q] != 0.0f);
            if (vv[q] != 0.0f) {
                int pos = cnt + __popcll(m & ((1ull << lane) - 1ull));
                if (pos < CAP) {
                    ellc[base + pos] = c0 + lane * 4 + q;
                    ellv[base + pos] = vv[q];
                }
            }
            cnt += __popcll(m);
        }
    }
    if (lane == 0) rcnt[row] = cnt < CAP ? cnt : CAP;
}

struct Params {
    const int*   ellc; const float* ellv; const int* rcnt;
    const float* x;
    const float *eWr, *ebr, *eWu, *ebu, *eWc, *ebc;
    const float *dWr, *dbr, *dWu, *dbu, *dWc, *dbc;
    const float *W1, *b1, *W2, *b2;
    float *XHh, *XHx, *X1h, *X1x, *XCh, *XCx, *Y1h, *Y1x, *U;
    unsigned* bar;
    float* out;
};

// ELL-broadcast diffusion: acch = (S@Xh)[n][lane], accx = (S@Xx)[n][lane>>5]
__device__ __forceinline__ void diffuse(const int* __restrict__ ellc,
                                        const float* __restrict__ ellv,
                                        int n, int cnt, int lane,
                                        const float* __restrict__ Xh,
                                        const float* __restrict__ Xx,
                                        float& acch, float& accx) {
    const int base = n * CAP;
    int colk = 0; float valk = 0.f;
    if (lane < cnt) { colk = ellc[base + lane]; valk = ellv[base + lane]; }
    acch = 0.f; accx = 0.f;
    const int bx = lane >> 5;
    for (int k = 0; k < cnt; ++k) {
        const int   c = __shfl(colk, k);
        const float v = __shfl(valk, k);
        acch = fmaf(v, Xh[c * 64 + lane], acch);   // 256B coalesced row
        accx = fmaf(v, Xx[c * 2 + bx], accx);      // one 8B segment
    }
}

__global__ __launch_bounds__(BLK, 2) void dcrnn_persist(Params P) {
    const int lane = threadIdx.x & 63;
    const int wav  = blockIdx.x * (BLK / 64) + (threadIdx.x >> 6);
    const int NW   = GRD * (BLK / 64);
    int barRound = 0;

    auto BAR = [&]() {
        ++barRound;
        __syncthreads();
        if (threadIdx.x == 0) {
            const unsigned g = (unsigned)blockIdx.x / BPG;
            unsigned old = __hip_atomic_fetch_add(&P.bar[16 + g * 16], 1u,
                               __ATOMIC_ACQ_REL, __HIP_MEMORY_SCOPE_AGENT);
            if (old == (unsigned)(barRound * BPG) - 1u)
                __hip_atomic_fetch_add(&P.bar[0], 1u,
                    __ATOMIC_ACQ_REL, __HIP_MEMORY_SCOPE_AGENT);
            while (__hip_atomic_load(&P.bar[0], __ATOMIC_RELAXED,
                                     __HIP_MEMORY_SCOPE_AGENT)
                   < (unsigned)(barRound * NGROUPS))
                __builtin_amdgcn_s_sleep(8);
            (void)__hip_atomic_load(&P.bar[0], __ATOMIC_ACQUIRE,
                                    __HIP_MEMORY_SCOPE_AGENT);
        }
        __syncthreads();
    };

    // ---- init: XHh = 0, XHx = x[:, t=0] ----
    for (int i = blockIdx.x * BLK + threadIdx.x; i < NV * 64; i += GRD * BLK)
        P.XHh[i] = 0.f;
    for (int i = blockIdx.x * BLK + threadIdx.x; i < NV * 2; i += GRD * BLK) {
        int n = i >> 1, b = i & 1;
        P.XHx[i] = P.x[((size_t)b * TT) * NV + n];
    }
    BAR();

    for (int cell = 0; cell < 2 * TT; ++cell) {
        const bool enc = cell < TT;
        const float* Wr = enc ? P.eWr : P.dWr;
        const float* br = enc ? P.ebr : P.dbr;
        const float* Wu = enc ? P.eWu : P.dWu;
        const float* bu = enc ? P.ebu : P.dbu;
        const float* Wc = enc ? P.eWc : P.dWc;
        const float* bc = enc ? P.ebc : P.dbc;
        const int mode = enc ? ((cell + 1 < TT) ? 0 : 1) : 2;   // next-x source

        // ---- S1: X1 = S @ XH ----
        for (int n = wav; n < NV; n += NW) {
            float ah, ax;
            diffuse(P.ellc, P.ellv, n, P.rcnt[n], lane, P.XHh, P.XHx, ah, ax);
            P.X1h[n * 64 + lane] = ah;
            if ((lane & 31) == 0) P.X1x[n * 2 + (lane >> 5)] = ax;
        }
        BAR();

        // ---- S2: X2 = S @ X1 (in-wave); r,u gates; XC = [x, r*h] ----
        for (int n = wav; n < NV; n += NW) {
            const int j = lane & 31, b = lane >> 5, jb = b << 5;
            float x2h, x2x;
            diffuse(P.ellc, P.ellv, n, P.rcnt[n], lane, P.X1h, P.X1x, x2h, x2x);
            const float xh_l = P.XHh[n * 64 + lane];
            const float x1_l = P.X1h[n * 64 + lane];
            const float xhx  = P.XHx[n * 2 + b];
            const float x1x  = P.X1x[n * 2 + b];
            float accr = br[j], accu = bu[j];
            accr = fmaf(xhx, Wr[j], accr);            accu = fmaf(xhx, Wu[j], accu);
            accr = fmaf(x1x, Wr[33 * 32 + j], accr);  accu = fmaf(x1x, Wu[33 * 32 + j], accu);
            accr = fmaf(x2x, Wr[66 * 32 + j], accr);  accu = fmaf(x2x, Wu[66 * 32 + j], accu);
#pragma unroll
            for (int m = 0; m < 32; ++m) {
                float f = __shfl(xh_l, jb + m);
                accr = fmaf(f, Wr[(1 + m) * 32 + j], accr);
                accu = fmaf(f, Wu[(1 + m) * 32 + j], accu);
            }
#pragma unroll
            for (int m = 0; m < 32; ++m) {
                float f = __shfl(x1_l, jb + m);
                accr = fmaf(f, Wr[(34 + m) * 32 + j], accr);
                accu = fmaf(f, Wu[(34 + m) * 32 + j], accu);
            }
#pragma unroll
            for (int m = 0; m < 32; ++m) {
                float f = __shfl(x2h, jb + m);
                accr = fmaf(f, Wr[(67 + m) * 32 + j], accr);
                accu = fmaf(f, Wu[(67 + m) * 32 + j], accu);
            }
            const float rg = 1.f / (1.f + expf(-accr));
            const float ug = 1.f / (1.f + expf(-accu));
            P.U[n * 64 + lane]   = ug;
            P.XCh[n * 64 + lane] = rg * xh_l;
            if (j == 0) P.XCx[n * 2 + b] = xhx;
        }
        BAR();

        // ---- S3: Y1 = S @ XC ----
        for (int n = wav; n < NV; n += NW) {
            float ah, ax;
            diffuse(P.ellc, P.ellv, n, P.rcnt[n], lane, P.XCh, P.XCx, ah, ax);
            P.Y1h[n * 64 + lane] = ah;
            if ((lane & 31) == 0) P.Y1x[n * 2 + (lane >> 5)] = ax;
        }
        BAR();

        // ---- S4: Y2 = S @ Y1; c = tanh; h = u*h+(1-u)*c; next x ----
        for (int n = wav; n < NV; n += NW) {
            const int j = lane & 31, b = lane >> 5, jb = b << 5;
            float y2h, y2x;
            diffuse(P.ellc, P.ellv, n, P.rcnt[n], lane, P.Y1h, P.Y1x, y2h, y2x);
            const float xc_l = P.XCh[n * 64 + lane];
            const float y1_l = P.Y1h[n * 64 + lane];
            const float xcx  = P.XCx[n * 2 + b];
            const float y1x  = P.Y1x[n * 2 + b];
            float acc = bc[j];
            acc = fmaf(xcx, Wc[j], acc);
            acc = fmaf(y1x, Wc[33 * 32 + j], acc);
            acc = fmaf(y2x, Wc[66 * 32 + j], acc);
#pragma unroll
            for (int m = 0; m < 32; ++m)
                acc = fmaf(__shfl(xc_l, jb + m), Wc[(1 + m) * 32 + j], acc);
#pragma unroll
            for (int m = 0; m < 32; ++m)
                acc = fmaf(__shfl(y1_l, jb + m), Wc[(34 + m) * 32 + j], acc);
#pragma unroll
            for (int m = 0; m < 32; ++m)
                acc = fmaf(__shfl(y2h, jb + m), Wc[(67 + m) * 32 + j], acc);
            const float cc = tanhf(acc);
            const float u  = P.U[n * 64 + lane];
            const float h  = u * P.XHh[n * 64 + lane] + (1.f - u) * cc;
            P.XHh[n * 64 + lane] = h;
            if (mode == 2) {
                // decoder head: z = relu(h@W1+b1); pred = z@W2+b2
                float z = P.b1[j];
#pragma unroll
                for (int m = 0; m < 32; ++m)
                    z = fmaf(__shfl(h, jb + m), P.W1[m * 32 + j], z);
                z = fmaxf(z, 0.f);
                float pz = z * P.W2[j];
#pragma unroll
                for (int off = 16; off; off >>= 1) pz += __shfl_xor(pz, off);
                if (j == 0) {
                    const float pred = pz + P.b2[0];
                    P.out[((size_t)b * TT + (cell - TT)) * NV + n] = pred;
                    P.XHx[n * 2 + b] = pred;
                }
            } else if (j == 0) {
                P.XHx[n * 2 + b] = (mode == 0)
                    ? P.x[((size_t)b * TT + (cell + 1)) * NV + n] : 0.f;
            }
        }
        BAR();
    }
}

extern "C" void kernel_launch(void* const* d_in, const int* in_sizes, int n_in,
                              void* d_out, int out_size, void* d_ws, size_t ws_size,
                              hipStream_t stream) {
    const float* x   = (const float*)d_in[0];
    // d_in[1] = edge_index (gso already encodes it)
    const float* gso = (const float*)d_in[2];

    char* p = (char*)d_ws;
    auto alloc = [&](size_t bytes) {
        char* q = p;
        p += (bytes + 255) & ~(size_t)255;
        return q;
    };
    int*      ellc = (int*)     alloc((size_t)NV * CAP * 4);
    float*    ellv = (float*)   alloc((size_t)NV * CAP * 4);
    int*      rcnt = (int*)     alloc((size_t)NV * 4);
    unsigned* bar  = (unsigned*)alloc(544 * 4);
    float*    XHh  = (float*)   alloc((size_t)NV * 64 * 4);
    float*    XHx  = (float*)   alloc((size_t)NV * 2 * 4);
    float*    X1h  = (float*)   alloc((size_t)NV * 64 * 4);
    float*    X1x  = (float*)   alloc((size_t)NV * 2 * 4);
    float*    XCh  = (float*)   alloc((size_t)NV * 64 * 4);
    float*    XCx  = (float*)   alloc((size_t)NV * 2 * 4);
    float*    Y1h  = (float*)   alloc((size_t)NV * 64 * 4);
    float*    Y1x  = (float*)   alloc((size_t)NV * 2 * 4);
    float*    U    = (float*)   alloc((size_t)NV * 64 * 4);

    hipLaunchKernelGGL(build_ell, dim3(NV / 4), dim3(256), 0, stream,
                       gso, ellc, ellv, rcnt, bar);

    Params P;
    P.ellc = ellc; P.ellv = ellv; P.rcnt = rcnt;
    P.x = x;
    P.eWr = (const float*)d_in[3];  P.ebr = (const float*)d_in[4];
    P.eWu = (const float*)d_in[5];  P.ebu = (const float*)d_in[6];
    P.eWc = (const float*)d_in[7];  P.ebc = (const float*)d_in[8];
    P.dWr = (const float*)d_in[9];  P.dbr = (const float*)d_in[10];
    P.dWu = (const float*)d_in[11]; P.dbu = (const float*)d_in[12];
    P.dWc = (const float*)d_in[13]; P.dbc = (const float*)d_in[14];
    P.W1  = (const float*)d_in[15]; P.b1  = (const float*)d_in[16];
    P.W2  = (const float*)d_in[17]; P.b2  = (const float*)d_in[18];
    P.XHh = XHh; P.XHx = XHx; P.X1h = X1h; P.X1x = X1x;
    P.XCh = XCh; P.XCx = XCx; P.Y1h = Y1h; P.Y1x = Y1x; P.U = U;
    P.bar = bar;
    P.out = (float*)d_out;

    hipLaunchKernelGGL(dcrnn_persist, dim3(GRD), dim3(BLK), 0, stream, P);
}